// Round 7
// baseline (249.839 us; speedup 1.0000x reference)
//
#include <hip/hip_runtime.h>
#include <hip/hip_bf16.h>
#include <math.h>

#define B_ 2
#define H_ 12
#define S_ 1024
#define D_ 128
#define BH_ (B_ * H_)
#define SCALE 0.08838834764831843f

#define QPAD 16
#define QROWS (S_ + QPAD)          /* 1040 */

/* prep_a grid segmentation */
#define NB_KH   768                /* 24 bh * 32 k-tiles */
#define NB_QP   3120               /* 24*1040*128 / 1024 */
#define NB_VT   3072               /* 24*32*4 */
#define NB_PREPA (NB_KH + NB_QP + NB_VT)

typedef __attribute__((ext_vector_type(8))) short short8;
typedef __attribute__((ext_vector_type(4))) float floatx4;

__device__ __forceinline__ unsigned short f2b(float f) {
    return __builtin_bit_cast(unsigned short, __float2bfloat16(f));
}

// ---- prep A: Khat fragments + Q pad/cvt + V permute -------------------------
// KH: Khat fragment-major. Block (bh*32+kt) is 24576 ushorts: [c24][nt2][ln64][e8]
//     Khat[k=kt*32+nt*16+(ln&15)][col=c*32+(ln>>4)*8+e]
//     Khat[k][i*128+d] = sum_j W[h][i][j]*SCALE * K[k+j-5][d].
// QP: Q -> bf16 row-major, 16 zero rows of top padding.
// VT: VhF[bh*32+kt][nd8][ln64][e8] = V (sigma-permuted for swapped-MFMA PV).
__global__ __launch_bounds__(256) void prep_a_kernel(
    const float* __restrict__ Q, const float* __restrict__ K,
    const float* __restrict__ V, const float* __restrict__ W,
    unsigned short* __restrict__ Qp, unsigned short* __restrict__ KhF,
    unsigned short* __restrict__ VhF)
{
    __shared__ __align__(16) union {
        float kld[42][132];       /* 22,176 B, padded */
        float vt_ls[32][33];
    } sm;
    const int blk = blockIdx.x;
    const int tid = threadIdx.x;

    if (blk < NB_KH) {
        const int bh = blk >> 5, kt = blk & 31;
        const int h = bh % H_;
        const int k0 = kt * 32;
        for (int p = tid; p < 42 * 32; p += 256) {
            const int r = p >> 5, c4 = (p & 31) * 4;
            const int gk = k0 - 5 + r;
            float4 v = make_float4(0.f, 0.f, 0.f, 0.f);
            if (gk >= 0 && gk < S_)
                v = *(const float4*)(K + ((size_t)bh * S_ + gk) * D_ + c4);
            *(float4*)&sm.kld[r][c4] = v;
        }
        __syncthreads();
        const int wv = tid >> 6, ln = tid & 63;
        const float* Wh = W + h * 66;
        const size_t obase = (size_t)blk * 24576;
        #pragma unroll
        for (int nt = 0; nt < 2; ++nt) {
            const int lr = nt * 16 + (ln & 15);
            const int d0 = wv * 32 + (ln >> 4) * 8;
            float a[6][8];
            #pragma unroll
            for (int i = 0; i < 6; ++i)
                #pragma unroll
                for (int e = 0; e < 8; ++e) a[i][e] = 0.f;
            #pragma unroll
            for (int j = 0; j < 11; ++j) {
                const float4 v0 = *(const float4*)&sm.kld[lr + j][d0];
                const float4 v1 = *(const float4*)&sm.kld[lr + j][d0 + 4];
                #pragma unroll
                for (int i = 0; i < 6; ++i) {
                    const float w = Wh[i * 11 + j];
                    a[i][0] += w * v0.x; a[i][1] += w * v0.y;
                    a[i][2] += w * v0.z; a[i][3] += w * v0.w;
                    a[i][4] += w * v1.x; a[i][5] += w * v1.y;
                    a[i][6] += w * v1.z; a[i][7] += w * v1.w;
                }
            }
            #pragma unroll
            for (int i = 0; i < 6; ++i) {
                short8 o;
                #pragma unroll
                for (int e = 0; e < 8; ++e) o[e] = (short)f2b(a[i][e] * SCALE);
                *(short8*)(KhF + obase + (size_t)(((i * 4 + wv) * 2 + nt) * 64 + ln) * 8) = o;
            }
        }
    } else if (blk < NB_KH + NB_QP) {
        const int idx = (blk - NB_KH) * 256 + tid;
        const size_t e0 = (size_t)idx * 4;
        const int bh = (int)(e0 / ((size_t)QROWS * D_));
        const int rem = (int)(e0 - (size_t)bh * QROWS * D_);
        const int r = rem / D_;
        const int d = rem - r * D_;
        const int sr = r - QPAD;
        float4 v = make_float4(0.f, 0.f, 0.f, 0.f);
        if (sr >= 0 && sr < S_)
            v = *(const float4*)(Q + ((size_t)bh * S_ + sr) * D_ + d);
        ushort4 o; o.x = f2b(v.x); o.y = f2b(v.y); o.z = f2b(v.z); o.w = f2b(v.w);
        *(ushort4*)(Qp + ((size_t)bh * QROWS + r) * D_ + d) = o;
    } else {
        const int b2 = blk - (NB_KH + NB_QP);
        const int dt = b2 & 3, ktl = (b2 >> 2) & 31, bh = b2 >> 7;
        const int lk = tid >> 3, ld = (tid & 7) * 4;
        const float4 v4 = *(const float4*)(V + ((size_t)bh * S_ + ktl * 32 + lk) * D_ + dt * 32 + ld);
        sm.vt_ls[lk][ld + 0] = v4.x; sm.vt_ls[lk][ld + 1] = v4.y;
        sm.vt_ls[lk][ld + 2] = v4.z; sm.vt_ls[lk][ld + 3] = v4.w;
        __syncthreads();
        const int lk2 = tid >> 3, lc = (tid & 7) * 4;
        const int pb = ((lc >> 3) << 2) | (((lc >> 2) & 1) << 4);   // sigma
        const int d = dt * 32 + lk2;
        const int nd = d >> 4, l15v = d & 15;
        ushort4 o;
        o.x = f2b(sm.vt_ls[pb + 0][lk2]); o.y = f2b(sm.vt_ls[pb + 1][lk2]);
        o.z = f2b(sm.vt_ls[pb + 2][lk2]); o.w = f2b(sm.vt_ls[pb + 3][lk2]);
        const size_t addr = ((size_t)((bh * 32 + ktl) * 8 + nd) * 64
                             + (lc >> 3) * 16 + l15v) * 8 + (lc & 7);
        *(ushort4*)(VhF + addr) = o;
    }
}

// ---- prep B: causal-band correction table ----------------------------------
// Corr[bh][q][d] = sum_{i,j: j-i>d} Ws[i,j]*(Q[q-5+i].K[q-5+i+(j-i-d)])
// K panel staged in LDS (the scattered-read side); Q rows read from global
// with 16-lane broadcast (uniform addresses across the dsl lanes).
__global__ __launch_bounds__(256) void prep_corr_kernel(
    const float* __restrict__ Q, const float* __restrict__ K,
    const float* __restrict__ W, float* __restrict__ Corr)
{
    __shared__ __align__(16) struct {
        float Ks[78][132];        /* rows q0c-4 .. q0c+73; 41,184 B */
        float band[69][16];
    } sm;
    const int cb = blockIdx.x;
    const int tid = threadIdx.x;
    const int bh = cb >> 4, q0c = (cb & 15) * 64;
    const int h = bh % H_;

    for (int p = tid; p < 78 * 32; p += 256) {
        const int r = p >> 5, c4 = (p & 31) * 4;
        const int gk = q0c - 4 + r;
        float4 v = make_float4(0.f, 0.f, 0.f, 0.f);
        if (gk >= 0 && gk < S_)
            v = *(const float4*)(K + ((size_t)bh * S_ + gk) * D_ + c4);
        *(float4*)&sm.Ks[r][c4] = v;
    }
    __syncthreads();
    // band[r][dsl] = Q[q0c-5+r] . K[q0c-5+r + dsl+1]  (= Q_global . Ks[r+dsl])
    for (int s = tid; s < 69 * 16; s += 256) {
        const int r = s >> 4, dsl = s & 15;
        float v = 0.f;
        const int qp = q0c - 5 + r;
        if (dsl < 10 && qp >= 0 && qp + dsl + 1 < S_) {
            const float4* qr = (const float4*)(Q + ((size_t)bh * S_ + qp) * D_);
            const float4* kr = (const float4*)&sm.Ks[r + dsl][0];
            #pragma unroll 8
            for (int c = 0; c < 32; ++c) {
                const float4 a = qr[c], b = kr[c];
                v += a.x * b.x + a.y * b.y + a.z * b.z + a.w * b.w;
            }
        }
        sm.band[r][dsl] = v;
    }
    __syncthreads();
    for (int e = tid; e < 64 * 16; e += 256) {
        const int ql = e >> 4, d = e & 15;
        float v = 0.f;
        if (d <= 10) {
            for (int i2 = 0; i2 < 6; ++i2)
                for (int j = i2 + d + 1; j < 11; ++j)
                    v += W[h * 66 + i2 * 11 + j] * SCALE * sm.band[ql + i2][j - i2 - d - 1];
        }
        Corr[((size_t)bh << 14) + ((size_t)(q0c + ql) << 4) + d] = v;
    }
}

// ---- main fused kernel ------------------------------------------------------
// 1536 blocks x 256 threads, free-run (no LDS, no barriers). Every MFMA operand
// load is a coalesced 1KB global read (KhF/VhF fragment-major, L2-resident).
// Each wave owns one 16-row q-strip and 1/4 of its k-tiles (balanced split);
// no-max softmax -> partials are plain sums; merge combines the 4 k-splits.
__global__ __launch_bounds__(256, 3) void conv_attn_mfma(
    const unsigned short* __restrict__ Qp,   // [24][1040][128] bf16
    const unsigned short* __restrict__ KhF,  // fragment-major Khat
    const unsigned short* __restrict__ VhF,  // fragment-major permuted V
    const float* __restrict__ Corr,          // [24][1024][16]  f32
    float* __restrict__ O,                   // ks=0 partial (final out)
    float* __restrict__ Op1, float* __restrict__ Op2, float* __restrict__ Op3,
    float* __restrict__ L0, float* __restrict__ L1,
    float* __restrict__ L2, float* __restrict__ L3)
{
    const int tid = threadIdx.x;
    const int wv = tid >> 6;        // 0..3
    const int ln = tid & 63;
    const int l15 = ln & 15;
    const int qd = ln >> 4;

    // 1536 blocks = 8 XCD x 3 bh x 16 sg x 4 ks (bh's Khat stays in one L2)
    const int bid = blockIdx.x;
    const int xcd = bid & 7;
    const int slot = bid >> 3;                 // 0..191
    const int bh = xcd * 3 + slot / 64;
    const int inner = slot & 63;
    const int sg = 15 - (inner >> 2);          // heavy strip-groups first
    const int ks = inner & 3;

    const int s = sg * 4 + wv;                 // strip 0..63
    const int qw0 = s * 16;                    // wave's 16 q-rows
    const int ktw = s >> 1;                    // wave's last needed k-tile
    const int n = ktw + 1;                     // total tiles for this strip
    const int qtr = n >> 2, rem = n & 3;
    const int cnt = qtr + (ks < rem ? 1 : 0);  // tiles this split handles
    const int klo = ks * qtr + (ks < rem ? ks : rem);

    const unsigned short* Khb = KhF + (size_t)(bh * 32) * 24576 + ln * 8;
    const unsigned short* Vhb = VhF + (size_t)(bh * 32) * 4096 + ln * 8;
    const float* Cb = Corr + ((size_t)bh << 14);

    // ---- Q B-fragments: register-resident ---------------------------------
    short8 qf[6][4];
    {
        const unsigned short* qbase =
            Qp + ((size_t)bh * QROWS + qw0 + 11 + l15) * D_ + qd * 8;
        #pragma unroll
        for (int i = 0; i < 6; ++i)
            #pragma unroll
            for (int kc = 0; kc < 4; ++kc)
                qf[i][kc] = *(const short8*)(qbase + (size_t)i * D_ + kc * 32);
    }

    floatx4 acc[8];
    #pragma unroll
    for (int nd = 0; nd < 8; ++nd) acc[nd] = (floatx4){0.f, 0.f, 0.f, 0.f};
    float l_run = 0.f;

    for (int t = 0; t < cnt; ++t) {
        const int kt = klo + t;
        const int k0 = kt * 32;
        const unsigned short* A = Khb + (size_t)kt * 24576;

        short8 vf[8];
        #pragma unroll
        for (int nd = 0; nd < 8; ++nd)
            vf[nd] = *(const short8*)(Vhb + (size_t)kt * 4096 + nd * 512);

        floatx4 s0 = {0.f, 0.f, 0.f, 0.f}, s1 = {0.f, 0.f, 0.f, 0.f};
        #pragma unroll
        for (int c = 0; c < 24; ++c) {
            const short8 a0 = *(const short8*)(A + c * 1024);
            const short8 a1 = *(const short8*)(A + c * 1024 + 512);
            const short8 b = qf[c >> 2][c & 3];
            s0 = __builtin_amdgcn_mfma_f32_16x16x32_bf16(a0, b, s0, 0, 0, 0);
            s1 = __builtin_amdgcn_mfma_f32_16x16x32_bf16(a1, b, s1, 0, 0, 0);
        }

        // ---- no-max softmax; lane l15 = q-row -----------------------------
        const bool need_corr = (kt >= ktw - 1);
        const int qrow = qw0 + l15;
        float sum = 0.f;
        short8 pbv;
        #pragma unroll
        for (int nt = 0; nt < 2; ++nt)
            #pragma unroll
            for (int rg = 0; rg < 4; ++rg) {
                const int kcol = k0 + nt * 16 + qd * 4 + rg;
                float v = nt ? s1[rg] : s0[rg];
                if (need_corr) {
                    const int dd = qrow - kcol;
                    if (dd >= 0 && dd <= 10) v -= Cb[(qrow << 4) + dd];
                }
                const float p = (kcol <= qrow) ? __expf(v) : 0.f;
                sum += p;
                pbv[nt * 4 + rg] = (short)f2b(p);
            }
        sum += __shfl_xor(sum, 16);
        sum += __shfl_xor(sum, 32);
        l_run += sum;

        // ---- P @ V (pbv order matches sigma-permuted VhF) -----------------
        #pragma unroll
        for (int nd = 0; nd < 8; ++nd)
            acc[nd] = __builtin_amdgcn_mfma_f32_16x16x32_bf16(pbv, vf[nd], acc[nd], 0, 0, 0);
    }

    // ---- write this split's partial (unnormalized; zeros when cnt==0) -----
    float* Ob = (ks == 0) ? O : (ks == 1) ? Op1 : (ks == 2) ? Op2 : Op3;
    float* Lb = (ks == 0) ? L0 : (ks == 1) ? L1 : (ks == 2) ? L2 : L3;
    if (qd == 0) Lb[bh * S_ + qw0 + l15] = l_run;
    #pragma unroll
    for (int rg = 0; rg < 4; ++rg) {
        const int row = qw0 + qd * 4 + rg;
        float* orow = Ob + ((size_t)bh * S_ + row) * D_;
        #pragma unroll
        for (int nd = 0; nd < 8; ++nd)
            orow[nd * 16 + l15] = acc[nd][rg];
    }
}

// ---- merge the four k-split partials ---------------------------------------
__global__ __launch_bounds__(256) void merge_kernel(
    float* __restrict__ O,
    const float* __restrict__ Op1, const float* __restrict__ Op2,
    const float* __restrict__ Op3,
    const float* __restrict__ L0, const float* __restrict__ L1,
    const float* __restrict__ L2, const float* __restrict__ L3)
{
    const int idx = blockIdx.x * 256 + threadIdx.x;   // float4 index
    const int row = idx >> 5;                          // bh*1024 + q
    const float inv = 1.f / (L0[row] + L1[row] + L2[row] + L3[row]);
    const float4 a = ((const float4*)O)[idx];
    const float4 b = ((const float4*)Op1)[idx];
    const float4 c = ((const float4*)Op2)[idx];
    const float4 d = ((const float4*)Op3)[idx];
    float4 o;
    o.x = (a.x + b.x + c.x + d.x) * inv;
    o.y = (a.y + b.y + c.y + d.y) * inv;
    o.z = (a.z + b.z + c.z + d.z) * inv;
    o.w = (a.w + b.w + c.w + d.w) * inv;
    ((float4*)O)[idx] = o;
}

extern "C" void kernel_launch(void* const* d_in, const int* in_sizes, int n_in,
                              void* d_out, int out_size, void* d_ws, size_t ws_size,
                              hipStream_t stream) {
    const float* Q = (const float*)d_in[0];
    const float* K = (const float*)d_in[1];
    const float* V = (const float*)d_in[2];
    const float* W = (const float*)d_in[3];
    float* O = (float*)d_out;

    // ws layout (~86 MB)
    unsigned short* Qp  = (unsigned short*)d_ws;                        // 6,389,760
    unsigned short* KhF = (unsigned short*)((char*)d_ws + 6389760);     // 37,748,736
    unsigned short* VhF = (unsigned short*)((char*)d_ws + 44138496);    // 6,291,456
    float*          Cr  = (float*)((char*)d_ws + 50429952);             // 1,572,864
    float*          Op1 = (float*)((char*)d_ws + 52002816);             // 12,582,912
    float*          Op2 = (float*)((char*)d_ws + 64585728);             // 12,582,912
    float*          Op3 = (float*)((char*)d_ws + 77168640);             // 12,582,912
    float*          L0  = (float*)((char*)d_ws + 89751552);             // 98,304
    float*          L1  = (float*)((char*)d_ws + 89849856);             // 98,304
    float*          L2  = (float*)((char*)d_ws + 89948160);             // 98,304
    float*          L3  = (float*)((char*)d_ws + 90046464);             // 98,304

    prep_a_kernel<<<dim3(NB_PREPA), dim3(256), 0, stream>>>(Q, K, V, W, Qp, KhF, VhF);
    prep_corr_kernel<<<dim3(384), dim3(256), 0, stream>>>(Q, K, W, Cr);
    conv_attn_mfma<<<dim3(1536), dim3(256), 0, stream>>>(Qp, KhF, VhF, Cr, O,
                                                         Op1, Op2, Op3, L0, L1, L2, L3);
    merge_kernel<<<dim3(3072), dim3(256), 0, stream>>>(O, Op1, Op2, Op3, L0, L1, L2, L3);
}